// Round 9
// baseline (118.790 us; speedup 1.0000x reference)
//
#include <hip/hip_runtime.h>
#include <math.h>

#define NB 32768
#define NC 1000
#define ND 512
#define NTILES 63          // 63*16 = 1008 >= 1000 class columns
#define LOG2E 1.4426950408889634f
#define LN2 0.6931471805599453f
#define S2 14.426950408889634f   // (1/T) * log2(e)
#define NBUCKET 64

// fat-kernel block roles
#define CE_BLOCKS 512
#define SIM_BLOCKS 256
#define GRAM_BLOCKS 1008   // 63 class-tiles x 16 row-tile groups

typedef __attribute__((ext_vector_type(8))) short short8;
typedef __attribute__((ext_vector_type(4))) float f32x4;

__device__ __forceinline__ float fexp2(float x) {
    float r; asm("v_exp_f32 %0, %1" : "=v"(r) : "v"(x)); return r;
}
__device__ __forceinline__ float flog2(float x) {
    float r; asm("v_log_f32 %0, %1" : "=v"(r) : "v"(x)); return r;
}
__device__ __forceinline__ unsigned short bf16_rne(float f) {
    unsigned int u = __builtin_bit_cast(unsigned int, f);
    u += 0x7FFFu + ((u >> 16) & 1u);
    return (unsigned short)(u >> 16);
}
__device__ __forceinline__ short8 pack8f(float4 a, float4 b) {
    short8 s;
    s[0] = (short)bf16_rne(a.x); s[1] = (short)bf16_rne(a.y);
    s[2] = (short)bf16_rne(a.z); s[3] = (short)bf16_rne(a.w);
    s[4] = (short)bf16_rne(b.x); s[5] = (short)bf16_rne(b.y);
    s[6] = (short)bf16_rne(b.z); s[7] = (short)bf16_rne(b.w);
    return s;
}

// ---------------- normalize prototypes -> bf16 in MFMA FRAGMENT ORDER ----------------
// frag[tile*1024 + kk*64 + g*16 + r] (short8 units) = row (tile*16+r), cols 32*kk+8*g..+8.
__global__ __launch_bounds__(256) void norm_protos(const float* __restrict__ pro,
                                                   unsigned short* __restrict__ pbf) {
    const int row = blockIdx.x, t = threadIdx.x;   // grid 1024 rows (>=NC padded w/ zeros)
    const int tile = row >> 4, r = row & 15;
    const int kk = t >> 4, g = (t >> 2) & 3, slot = t & 3;
    unsigned int* dst = (unsigned int*)pbf +
        ((size_t)tile * 1024 + kk * 64 + g * 16 + r) * 4 + slot;
    if (row >= NC) { *dst = 0u; return; }  // zero pad rows (uniform per block)
    const float* rp = pro + (size_t)row * ND;
    const float x0 = rp[2 * t], x1 = rp[2 * t + 1];
    float ss = x0 * x0 + x1 * x1;
#pragma unroll
    for (int o = 1; o < 64; o <<= 1) ss += __shfl_xor(ss, o, 64);
    __shared__ float part[4];
    if ((t & 63) == 0) part[t >> 6] = ss;
    __syncthreads();
    const float nrm = sqrtf(part[0] + part[1] + part[2] + part[3]);
    const float sc = 1.0f / fmaxf(nrm, 1e-12f);
    *dst = (unsigned int)bf16_rne(x0 * sc) | ((unsigned int)bf16_rne(x1 * sc) << 16);
}

// ---------------- fat kernel: CE blocks + SIM blocks + GRAM blocks ----------------
// SIM: 16x16x32 MFMA swapped operands, D layout (m89): col=lane&15=feature row,
// class=(lane>>4)*4+reg. P tiles staged to LDS via global_load_lds (frag order is
// linear, so staging is a pure 16 KB linear copy), double-buffered, 1 barrier/tile.
// Wave holds 32 feature rows (2 row-groups); 4 independent MFMA chains.
__global__ __launch_bounds__(256, 1) void fat_kernel(const float* __restrict__ feat,
                                                     const float* __restrict__ logits,
                                                     const int* __restrict__ labels,
                                                     const unsigned short* __restrict__ pbf,
                                                     float* __restrict__ buckets) {
    __shared__ short8 lds[2][1024];   // 32 KiB (sim path only)
    __shared__ float wsum[4], wsum2[4];
    const int b = blockIdx.x;
    const int t = threadIdx.x;
    const int wid = t >> 6, lane = t & 63;
    const short8* frag = (const short8*)pbf;

    if (b < CE_BLOCKS) {
        // ================= CE path: 64 rows/block, 4 rows in flight per wave =======
        const int rowbase = b * 64 + wid * 16;
        const int q4 = lane >> 4, l16 = lane & 15;
        float localce = 0.f;
#pragma unroll 1
        for (int i = 0; i < 4; ++i) {
            const int row = rowbase + 4 * i + q4;
            const float* rp = logits + (size_t)row * NC;
            const float4* rp4 = (const float4*)rp;
            float4 xs[16];
#pragma unroll
            for (int j = 0; j < 15; ++j) {
                const float4 v = rp4[l16 + 16 * j];
                xs[j].x = v.x * LOG2E; xs[j].y = v.y * LOG2E;
                xs[j].z = v.z * LOG2E; xs[j].w = v.w * LOG2E;
            }
            if (l16 < 10) {  // idx = l16 + 240 < 250
                const float4 v = rp4[l16 + 240];
                xs[15].x = v.x * LOG2E; xs[15].y = v.y * LOG2E;
                xs[15].z = v.z * LOG2E; xs[15].w = v.w * LOG2E;
            } else {
                xs[15].x = xs[15].y = xs[15].z = xs[15].w = -INFINITY;
            }
            float m = -INFINITY;
#pragma unroll
            for (int j = 0; j < 16; ++j)
                m = fmaxf(m, fmaxf(fmaxf(xs[j].x, xs[j].y), fmaxf(xs[j].z, xs[j].w)));
#pragma unroll
            for (int o = 1; o <= 8; o <<= 1) m = fmaxf(m, __shfl_xor(m, o, 64));
            float s = 0.f;
#pragma unroll
            for (int j = 0; j < 16; ++j)
                s += fexp2(xs[j].x - m) + fexp2(xs[j].y - m) +
                     fexp2(xs[j].z - m) + fexp2(xs[j].w - m);
#pragma unroll
            for (int o = 1; o <= 8; o <<= 1) s += __shfl_xor(s, o, 64);
            if (l16 == 0) {
                int lab = labels[row];
                lab = lab < 0 ? 0 : (lab > NC - 1 ? NC - 1 : lab);
                localce += (m + flog2(s)) * LN2 - rp[lab];
            }
        }
#pragma unroll
        for (int o = 1; o < 64; o <<= 1) localce += __shfl_xor(localce, o, 64);
        if (lane == 0) wsum[wid] = localce;
        __syncthreads();
        if (t == 0)
            atomicAdd(buckets + 1024 + (b & (NBUCKET - 1)) * 16,
                      (wsum[0] + wsum[1] + wsum[2] + wsum[3]) * (1.0f / (float)NB));

    } else if (b < CE_BLOCKS + SIM_BLOCKS) {
        // ================= SIM path: 128 rows/block (32/wave), LDS-staged tiles =====
        const int sb = b - CE_BLOCKS;
        const int r16 = lane & 15, g = lane >> 4;
        const int rowbase = sb * 128 + wid * 32;

        // stage tile 0 (linear 16 KB copy; dest = wave-uniform base + lane*16)
#pragma unroll
        for (int q = 0; q < 4; ++q) {
            const int id = t + 256 * q;
            __builtin_amdgcn_global_load_lds(
                (const __attribute__((address_space(1))) unsigned int*)(frag + id),
                (__attribute__((address_space(3))) unsigned int*)(&lds[0][0] + id), 16, 0, 0);
        }

        // feature fragments for 2 row-groups (rows rowbase+r16, rowbase+16+r16)
        short8 bf0[16], bf1[16];
        {
            const float* f0 = feat + (size_t)(rowbase + r16) * ND + 8 * g;
            const float* f1 = f0 + 16 * ND;
#pragma unroll
            for (int kk = 0; kk < 16; ++kk) {
                bf0[kk] = pack8f(*(const float4*)(f0 + 32 * kk), *(const float4*)(f0 + 32 * kk + 4));
                bf1[kk] = pack8f(*(const float4*)(f1 + 32 * kk), *(const float4*)(f1 + 32 * kk + 4));
            }
        }
        int lab0 = labels[rowbase + r16];
        int lab1 = labels[rowbase + 16 + r16];
        lab0 = lab0 < 0 ? 0 : (lab0 > NC - 1 ? NC - 1 : lab0);
        lab1 = lab1 < 0 ? 0 : (lab1 > NC - 1 ? NC - 1 : lab1);

        float m0 = -INFINITY, ls0 = 0.f, lv0 = 0.f;
        float m1 = -INFINITY, ls1 = 0.f, lv1 = 0.f;

        __syncthreads();  // tile 0 resident (barrier drains vmcnt)

#pragma unroll 1
        for (int ct = 0; ct < NTILES; ++ct) {
            const short8* cur = lds[ct & 1];
            if (ct + 1 < NTILES) {
                short8* nxt = lds[(ct + 1) & 1];
                const short8* src = frag + (ct + 1) * 1024;
#pragma unroll
                for (int q = 0; q < 4; ++q) {
                    const int id = t + 256 * q;
                    __builtin_amdgcn_global_load_lds(
                        (const __attribute__((address_space(1))) unsigned int*)(src + id),
                        (__attribute__((address_space(3))) unsigned int*)(nxt + id), 16, 0, 0);
                }
            }
            // 4 independent MFMA chains (2 row-groups x even/odd kk)
            f32x4 e0 = {0.f, 0.f, 0.f, 0.f}, o0 = {0.f, 0.f, 0.f, 0.f};
            f32x4 e1 = {0.f, 0.f, 0.f, 0.f}, o1 = {0.f, 0.f, 0.f, 0.f};
#pragma unroll
            for (int kk = 0; kk < 8; ++kk) {
                const short8 A = cur[kk * 64 + lane];
                const short8 A2 = cur[(8 + kk) * 64 + lane];
                e0 = __builtin_amdgcn_mfma_f32_16x16x32_bf16(A, bf0[kk], e0, 0, 0, 0);
                o0 = __builtin_amdgcn_mfma_f32_16x16x32_bf16(A2, bf0[8 + kk], o0, 0, 0, 0);
                e1 = __builtin_amdgcn_mfma_f32_16x16x32_bf16(A, bf1[kk], e1, 0, 0, 0);
                o1 = __builtin_amdgcn_mfma_f32_16x16x32_bf16(A2, bf1[8 + kk], o1, 0, 0, 0);
            }
            const int cbase = ct * 16 + g * 4;
            {   // row-group 0
                float x[4];
#pragma unroll
                for (int rI = 0; rI < 4; ++rI) {
                    const float v = (e0[rI] + o0[rI]) * S2;
                    x[rI] = (cbase + rI < NC) ? v : -INFINITY;  // bites only at ct==62
                    lv0 += (cbase + rI == lab0) ? v : 0.f;
                }
                const float tmax = fmaxf(fmaxf(x[0], x[1]), fmaxf(x[2], x[3]));
                const float mn = fmaxf(m0, tmax);
                ls0 *= fexp2(m0 - mn);  // =0 on first tile, =1 when no new max
                m0 = mn;
                ls0 += fexp2(x[0] - mn) + fexp2(x[1] - mn) + fexp2(x[2] - mn) + fexp2(x[3] - mn);
            }
            {   // row-group 1
                float x[4];
#pragma unroll
                for (int rI = 0; rI < 4; ++rI) {
                    const float v = (e1[rI] + o1[rI]) * S2;
                    x[rI] = (cbase + rI < NC) ? v : -INFINITY;
                    lv1 += (cbase + rI == lab1) ? v : 0.f;
                }
                const float tmax = fmaxf(fmaxf(x[0], x[1]), fmaxf(x[2], x[3]));
                const float mn = fmaxf(m1, tmax);
                ls1 *= fexp2(m1 - mn);
                m1 = mn;
                ls1 += fexp2(x[0] - mn) + fexp2(x[1] - mn) + fexp2(x[2] - mn) + fexp2(x[3] - mn);
            }
            __syncthreads();  // all waves done with cur; next tile resident
        }

        // merge the 4 lane-groups (g=0..3) holding the same feature rows
#pragma unroll
        for (int o = 16; o <= 32; o <<= 1) {
            {
                const float mo = __shfl_xor(m0, o, 64), lo = __shfl_xor(ls0, o, 64);
                lv0 += __shfl_xor(lv0, o, 64);
                const float mm = fmaxf(m0, mo);
                ls0 = ls0 * fexp2(m0 - mm) + lo * fexp2(mo - mm);
                m0 = mm;
            }
            {
                const float mo = __shfl_xor(m1, o, 64), lo = __shfl_xor(ls1, o, 64);
                lv1 += __shfl_xor(lv1, o, 64);
                const float mm = fmaxf(m1, mo);
                ls1 = ls1 * fexp2(m1 - mm) + lo * fexp2(mo - mm);
                m1 = mm;
            }
        }
        const float row0 = (m0 + flog2(ls0) - lv0) * LN2;  // replicated on 4 lanes
        const float row1 = (m1 + flog2(ls1) - lv1) * LN2;
        float mine = (row0 + row1) * (1.0f / (4.0f * (float)NB));
#pragma unroll
        for (int o = 1; o < 64; o <<= 1) mine += __shfl_xor(mine, o, 64);
        if (lane == 0) wsum2[wid] = mine;
        __syncthreads();
        if (t == 0)
            atomicAdd(buckets + (sb & (NBUCKET - 1)) * 16,
                      wsum2[0] + wsum2[1] + wsum2[2] + wsum2[3]);

    } else {
        // ================= GRAM path: exp-sum of off-diagonal Gram entries =========
        const int gb = b - CE_BLOCKS - SIM_BLOCKS;   // 0..1007
        const int ct = gb >> 4;                      // class tile 0..62 (A side)
        const int bx = gb & 15;                      // row-tile group 0..15
        const int r16 = lane & 15, g = lane >> 4;
        const int btile = bx * 4 + wid;              // feature-side tile 0..63 (pad zeros)
        const int irow = btile * 16 + r16;

        short8 af[16], bfr[16];
#pragma unroll
        for (int kk = 0; kk < 16; ++kk) {
            af[kk] = frag[(size_t)ct * 1024 + kk * 64 + lane];
            bfr[kk] = frag[(size_t)btile * 1024 + kk * 64 + lane];
        }
        f32x4 dacc = {0.f, 0.f, 0.f, 0.f};
#pragma unroll
        for (int kk = 0; kk < 16; ++kk)
            dacc = __builtin_amdgcn_mfma_f32_16x16x32_bf16(af[kk], bfr[kk], dacc, 0, 0, 0);

        float s = 0.f;
        if (irow < NC) {
            const int cbase = ct * 16 + g * 4;
#pragma unroll
            for (int rI = 0; rI < 4; ++rI) {
                const int j = cbase + rI;
                if (j < NC && j != irow) s += fexp2(dacc[rI] * LOG2E);
            }
        }
#pragma unroll
        for (int o = 1; o < 64; o <<= 1) s += __shfl_xor(s, o, 64);
        if (lane == 0) wsum[wid] = s;
        __syncthreads();
        if (t == 0)
            atomicAdd(buckets + 2048 + (gb & (NBUCKET - 1)) * 16,
                      wsum[0] + wsum[1] + wsum[2] + wsum[3]);
    }
}

// ---------------- final combine: sum buckets ----------------
__global__ void combine_kernel(const float* __restrict__ a, float* __restrict__ out) {
    const int t = threadIdx.x;  // 64 threads
    float s = a[t * 16], c = a[1024 + t * 16], gr = a[2048 + t * 16];
#pragma unroll
    for (int o = 1; o < 64; o <<= 1) {
        s += __shfl_xor(s, o, 64);
        c += __shfl_xor(c, o, 64);
        gr += __shfl_xor(gr, o, 64);
    }
    if (t == 0) out[0] = s + c + logf(gr) * (1.0f / (float)NC);
}

extern "C" void kernel_launch(void* const* d_in, const int* in_sizes, int n_in,
                              void* d_out, int out_size, void* d_ws, size_t ws_size,
                              hipStream_t stream) {
    const float* feat   = (const float*)d_in[0];  // [32768,512]
    const float* logits = (const float*)d_in[1];  // [32768,1000]
    const int*   labels = (const int*)d_in[2];    // [32768]
    const float* pro    = (const float*)d_in[3];  // [1000,512]
    float* out = (float*)d_out;

    float* acc = (float*)d_ws;  // buckets: [0]=sim, [1024]=ce, [2048]=gram (stride-16 floats)
    unsigned short* pbf = (unsigned short*)((char*)d_ws + 16384);  // frag-order bf16, 1 MiB

    hipMemsetAsync(d_ws, 0, 3072 * sizeof(float), stream);
    hipLaunchKernelGGL(norm_protos,    dim3(1024), dim3(256), 0, stream, pro, pbf);
    hipLaunchKernelGGL(fat_kernel,     dim3(CE_BLOCKS + SIM_BLOCKS + GRAM_BLOCKS),
                       dim3(256), 0, stream, feat, logits, labels, pbf, acc);
    hipLaunchKernelGGL(combine_kernel, dim3(1),    dim3(64),  0, stream, acc, out);
}

// Round 10
// 99.048 us; speedup vs baseline: 1.1993x; 1.1993x over previous
//
#include <hip/hip_runtime.h>
#include <math.h>

#define NB 32768
#define NC 1000
#define ND 512
#define NTILES 63          // 63*16 = 1008 >= 1000 class columns
#define LOG2E 1.4426950408889634f
#define LN2 0.6931471805599453f
#define S2 14.426950408889634f   // (1/T) * log2(e)
#define NBUCKET 64

typedef __attribute__((ext_vector_type(8))) short short8;
typedef __attribute__((ext_vector_type(4))) float f32x4;

__device__ __forceinline__ float fexp2(float x) {
    float r; asm("v_exp_f32 %0, %1" : "=v"(r) : "v"(x)); return r;
}
__device__ __forceinline__ float flog2(float x) {
    float r; asm("v_log_f32 %0, %1" : "=v"(r) : "v"(x)); return r;
}
__device__ __forceinline__ unsigned short bf16_rne(float f) {
    unsigned int u = __builtin_bit_cast(unsigned int, f);
    u += 0x7FFFu + ((u >> 16) & 1u);
    return (unsigned short)(u >> 16);
}
__device__ __forceinline__ short8 pack8f(float4 a, float4 b) {
    short8 s;
    s[0] = (short)bf16_rne(a.x); s[1] = (short)bf16_rne(a.y);
    s[2] = (short)bf16_rne(a.z); s[3] = (short)bf16_rne(a.w);
    s[4] = (short)bf16_rne(b.x); s[5] = (short)bf16_rne(b.y);
    s[6] = (short)bf16_rne(b.z); s[7] = (short)bf16_rne(b.w);
    return s;
}

// ---------------- normalize prototypes -> bf16 in MFMA FRAGMENT ORDER ----------------
// frag[tile*1024 + kk*64 + g*16 + r] (short8 units) = row (tile*16+r), cols 32*kk+8*g..+8.
__global__ __launch_bounds__(256) void norm_protos(const float* __restrict__ pro,
                                                   unsigned short* __restrict__ pbf) {
    const int row = blockIdx.x, t = threadIdx.x;   // grid 1024 rows (>=NC padded w/ zeros)
    const int tile = row >> 4, r = row & 15;
    const int kk = t >> 4, g = (t >> 2) & 3, slot = t & 3;
    unsigned int* dst = (unsigned int*)pbf +
        ((size_t)tile * 1024 + kk * 64 + g * 16 + r) * 4 + slot;
    if (row >= NC) { *dst = 0u; return; }  // zero pad rows (uniform per block)
    const float* rp = pro + (size_t)row * ND;
    const float x0 = rp[2 * t], x1 = rp[2 * t + 1];
    float ss = x0 * x0 + x1 * x1;
#pragma unroll
    for (int o = 1; o < 64; o <<= 1) ss += __shfl_xor(ss, o, 64);
    __shared__ float part[4];
    if ((t & 63) == 0) part[t >> 6] = ss;
    __syncthreads();
    const float nrm = sqrtf(part[0] + part[1] + part[2] + part[3]);
    const float sc = 1.0f / fmaxf(nrm, 1e-12f);
    *dst = (unsigned int)bf16_rne(x0 * sc) | ((unsigned int)bf16_rne(x1 * sc) << 16);
}

// ---------------- fat kernel: interleaved SIM / CE / GRAM blocks ----------------
// role = blockIdx%3 (mixes roles across every CU); idx = blockIdx/3 (0..1023 per role).
// SIM: 64 rows x half-the-classes per block; partial (m,ls,lv) -> workspace (no atomic).
// CE : 32 rows/block, 16-lane row-groups, 4 rows in flight.
// GRAM: 1008 active blocks, idx>=1008 exit.
__global__ __launch_bounds__(256, 3) void fat_kernel(const float* __restrict__ feat,
                                                     const float* __restrict__ logits,
                                                     const int* __restrict__ labels,
                                                     const unsigned short* __restrict__ pbf,
                                                     float* __restrict__ buckets,
                                                     float4* __restrict__ part) {
    __shared__ short8 lds[2][1024];   // 32 KiB (sim path only)
    __shared__ float wsum[4];
    const int role = blockIdx.x % 3;
    const int idx = blockIdx.x / 3;
    const int t = threadIdx.x;
    const int wid = t >> 6, lane = t & 63;
    const short8* frag = (const short8*)pbf;

    if (role == 0) {
        // ================= SIM: rows [rb*64, rb*64+64), class tiles [t0, t0+nt) ====
        const int rb = idx >> 1, ch = idx & 1;
        const int t0 = ch ? 32 : 0;
        const int nt = ch ? 31 : 32;
        const int r16 = lane & 15, g = lane >> 4;
        const int rowbase = rb * 64 + wid * 16;

        // stage first tile (linear 16 KB copy; dest = wave-uniform base + lane*16)
        {
            const short8* src = frag + t0 * 1024;
#pragma unroll
            for (int q = 0; q < 4; ++q) {
                const int id = t + 256 * q;
                __builtin_amdgcn_global_load_lds(
                    (const __attribute__((address_space(1))) unsigned int*)(src + id),
                    (__attribute__((address_space(3))) unsigned int*)(&lds[0][0] + id), 16, 0, 0);
            }
        }
        // feature fragments: bf[kk] = feat[row][32*kk + 8*g .. +8]
        short8 bf[16];
        {
            const float* f0 = feat + (size_t)(rowbase + r16) * ND + 8 * g;
#pragma unroll
            for (int kk = 0; kk < 16; ++kk)
                bf[kk] = pack8f(*(const float4*)(f0 + 32 * kk), *(const float4*)(f0 + 32 * kk + 4));
        }
        int lab0 = labels[rowbase + r16];
        lab0 = lab0 < 0 ? 0 : (lab0 > NC - 1 ? NC - 1 : lab0);

        float m0 = -INFINITY, ls0 = 0.f, lv0 = 0.f;
        __syncthreads();  // first tile resident

#pragma unroll 1
        for (int j = 0; j < nt; ++j) {
            const short8* cur = lds[j & 1];
            if (j + 1 < nt) {
                short8* nxt = lds[(j + 1) & 1];
                const short8* src = frag + (t0 + j + 1) * 1024;
#pragma unroll
                for (int q = 0; q < 4; ++q) {
                    const int id = t + 256 * q;
                    __builtin_amdgcn_global_load_lds(
                        (const __attribute__((address_space(1))) unsigned int*)(src + id),
                        (__attribute__((address_space(3))) unsigned int*)(nxt + id), 16, 0, 0);
                }
            }
            // 2 independent MFMA chains (even/odd kk)
            f32x4 aE = {0.f, 0.f, 0.f, 0.f}, aO = {0.f, 0.f, 0.f, 0.f};
#pragma unroll
            for (int kk = 0; kk < 8; ++kk) {
                aE = __builtin_amdgcn_mfma_f32_16x16x32_bf16(cur[kk * 64 + lane], bf[kk], aE, 0, 0, 0);
                aO = __builtin_amdgcn_mfma_f32_16x16x32_bf16(cur[(8 + kk) * 64 + lane], bf[8 + kk], aO, 0, 0, 0);
            }
            const int cbase = (t0 + j) * 16 + g * 4;
            float x[4];
#pragma unroll
            for (int rI = 0; rI < 4; ++rI) {
                const float v = (aE[rI] + aO[rI]) * S2;
                x[rI] = (cbase + rI < NC) ? v : -INFINITY;   // bites only at last tile
                lv0 += (cbase + rI == lab0) ? v : 0.f;
            }
            const float tmax = fmaxf(fmaxf(x[0], x[1]), fmaxf(x[2], x[3]));
            const float mn = fmaxf(m0, tmax);
            ls0 *= fexp2(m0 - mn);   // =0 on first tile, =1 when no new max
            m0 = mn;
            ls0 += fexp2(x[0] - mn) + fexp2(x[1] - mn) + fexp2(x[2] - mn) + fexp2(x[3] - mn);
            __syncthreads();  // all waves done with cur; next tile resident
        }

        // merge the 4 lane-groups (g=0..3); afterwards all lanes hold the row value
#pragma unroll
        for (int o = 16; o <= 32; o <<= 1) {
            const float mo = __shfl_xor(m0, o, 64), lo = __shfl_xor(ls0, o, 64);
            lv0 += __shfl_xor(lv0, o, 64);
            const float mm = fmaxf(m0, mo);
            ls0 = ls0 * fexp2(m0 - mm) + lo * fexp2(mo - mm);
            m0 = mm;
        }
        if (lane < 16) {
            float4 p; p.x = m0; p.y = ls0; p.z = lv0; p.w = 0.f;
            part[(size_t)(rowbase + r16) * 2 + ch] = p;
        }

    } else if (role == 1) {
        // ================= CE: 32 rows/block, 8 rows/wave ==========================
        const int rowbase = idx * 32 + wid * 8;
        const int q4 = lane >> 4, l16 = lane & 15;
        float localce = 0.f;
#pragma unroll 1
        for (int i = 0; i < 2; ++i) {
            const int row = rowbase + 4 * i + q4;
            const float* rp = logits + (size_t)row * NC;
            const float4* rp4 = (const float4*)rp;
            float4 xs[16];
#pragma unroll
            for (int j = 0; j < 15; ++j) {
                const float4 v = rp4[l16 + 16 * j];
                xs[j].x = v.x * LOG2E; xs[j].y = v.y * LOG2E;
                xs[j].z = v.z * LOG2E; xs[j].w = v.w * LOG2E;
            }
            if (l16 < 10) {  // idx = l16 + 240 < 250
                const float4 v = rp4[l16 + 240];
                xs[15].x = v.x * LOG2E; xs[15].y = v.y * LOG2E;
                xs[15].z = v.z * LOG2E; xs[15].w = v.w * LOG2E;
            } else {
                xs[15].x = xs[15].y = xs[15].z = xs[15].w = -INFINITY;
            }
            float m = -INFINITY;
#pragma unroll
            for (int j = 0; j < 16; ++j)
                m = fmaxf(m, fmaxf(fmaxf(xs[j].x, xs[j].y), fmaxf(xs[j].z, xs[j].w)));
#pragma unroll
            for (int o = 1; o <= 8; o <<= 1) m = fmaxf(m, __shfl_xor(m, o, 64));
            float s = 0.f;
#pragma unroll
            for (int j = 0; j < 16; ++j)
                s += fexp2(xs[j].x - m) + fexp2(xs[j].y - m) +
                     fexp2(xs[j].z - m) + fexp2(xs[j].w - m);
#pragma unroll
            for (int o = 1; o <= 8; o <<= 1) s += __shfl_xor(s, o, 64);
            if (l16 == 0) {
                int lab = labels[row];
                lab = lab < 0 ? 0 : (lab > NC - 1 ? NC - 1 : lab);
                localce += (m + flog2(s)) * LN2 - rp[lab];
            }
        }
#pragma unroll
        for (int o = 1; o < 64; o <<= 1) localce += __shfl_xor(localce, o, 64);
        if (lane == 0) wsum[wid] = localce;
        __syncthreads();
        if (t == 0)
            atomicAdd(buckets + 1024 + (idx & (NBUCKET - 1)) * 16,
                      (wsum[0] + wsum[1] + wsum[2] + wsum[3]) * (1.0f / (float)NB));

    } else {
        // ================= GRAM: exp-sum of off-diagonal Gram entries ==============
        if (idx >= 1008) return;
        const int ct = idx >> 4;                     // class tile 0..62 (A side)
        const int bx = idx & 15;                     // row-tile group 0..15
        const int r16 = lane & 15, g = lane >> 4;
        const int btile = bx * 4 + wid;              // feature-side tile 0..63 (pad zeros)
        const int irow = btile * 16 + r16;

        short8 af[16], bfr[16];
#pragma unroll
        for (int kk = 0; kk < 16; ++kk) {
            af[kk] = frag[(size_t)ct * 1024 + kk * 64 + lane];
            bfr[kk] = frag[(size_t)btile * 1024 + kk * 64 + lane];
        }
        f32x4 dacc = {0.f, 0.f, 0.f, 0.f};
#pragma unroll
        for (int kk = 0; kk < 16; ++kk)
            dacc = __builtin_amdgcn_mfma_f32_16x16x32_bf16(af[kk], bfr[kk], dacc, 0, 0, 0);

        float s = 0.f;
        if (irow < NC) {
            const int cbase = ct * 16 + g * 4;
#pragma unroll
            for (int rI = 0; rI < 4; ++rI) {
                const int j = cbase + rI;
                if (j < NC && j != irow) s += fexp2(dacc[rI] * LOG2E);
            }
        }
#pragma unroll
        for (int o = 1; o < 64; o <<= 1) s += __shfl_xor(s, o, 64);
        if (lane == 0) wsum[wid] = s;
        __syncthreads();
        if (t == 0)
            atomicAdd(buckets + 2048 + (idx & (NBUCKET - 1)) * 16,
                      wsum[0] + wsum[1] + wsum[2] + wsum[3]);
    }
}

// ---------------- merge SIM class-chunk partials -> sim buckets ----------------
__global__ __launch_bounds__(256) void simmerge_kernel(const float4* __restrict__ part,
                                                       float* __restrict__ buckets) {
    __shared__ float wsum[4];
    const int t = threadIdx.x, wid = t >> 6, lane = t & 63;
    const int row = blockIdx.x * 256 + t;
    const float4 p0 = part[(size_t)row * 2];
    const float4 p1 = part[(size_t)row * 2 + 1];
    const float M = fmaxf(p0.x, p1.x);
    const float LS = p0.y * fexp2(p0.x - M) + p1.y * fexp2(p1.x - M);
    float v = (M + flog2(LS) - (p0.z + p1.z)) * LN2 * (1.0f / (float)NB);
#pragma unroll
    for (int o = 1; o < 64; o <<= 1) v += __shfl_xor(v, o, 64);
    if (lane == 0) wsum[wid] = v;
    __syncthreads();
    if (t == 0)
        atomicAdd(buckets + (blockIdx.x & (NBUCKET - 1)) * 16,
                  wsum[0] + wsum[1] + wsum[2] + wsum[3]);
}

// ---------------- final combine: sum buckets ----------------
__global__ void combine_kernel(const float* __restrict__ a, float* __restrict__ out) {
    const int t = threadIdx.x;  // 64 threads
    float s = a[t * 16], c = a[1024 + t * 16], gr = a[2048 + t * 16];
#pragma unroll
    for (int o = 1; o < 64; o <<= 1) {
        s += __shfl_xor(s, o, 64);
        c += __shfl_xor(c, o, 64);
        gr += __shfl_xor(gr, o, 64);
    }
    if (t == 0) out[0] = s + c + logf(gr) * (1.0f / (float)NC);
}

extern "C" void kernel_launch(void* const* d_in, const int* in_sizes, int n_in,
                              void* d_out, int out_size, void* d_ws, size_t ws_size,
                              hipStream_t stream) {
    const float* feat   = (const float*)d_in[0];  // [32768,512]
    const float* logits = (const float*)d_in[1];  // [32768,1000]
    const int*   labels = (const int*)d_in[2];    // [32768]
    const float* pro    = (const float*)d_in[3];  // [1000,512]
    float* out = (float*)d_out;

    float* acc = (float*)d_ws;  // buckets: [0]=sim, [1024]=ce, [2048]=gram (stride-16 floats)
    unsigned short* pbf = (unsigned short*)((char*)d_ws + 16384);        // frag-order bf16, 1 MiB
    float4* part = (float4*)((char*)d_ws + (2u << 20));                  // [32768][2] partials, 1 MiB

    hipMemsetAsync(d_ws, 0, 3072 * sizeof(float), stream);
    hipLaunchKernelGGL(norm_protos,     dim3(1024), dim3(256), 0, stream, pro, pbf);
    hipLaunchKernelGGL(fat_kernel,      dim3(3072), dim3(256), 0, stream,
                       feat, logits, labels, pbf, acc, part);
    hipLaunchKernelGGL(simmerge_kernel, dim3(128),  dim3(256), 0, stream, part, acc);
    hipLaunchKernelGGL(combine_kernel,  dim3(1),    dim3(64),  0, stream, acc, out);
}